// Round 7
// baseline (502.589 us; speedup 1.0000x reference)
//
#include <hip/hip_runtime.h>

#define NUM_S 1024
#define NCOPY 4            // wave-group-private LDS histogram copies
#define NXCD 8             // global histogram replicas, one per XCD (XCC_ID)
#define SLOT_U64 8         // 64B stride: each (station,replica) slot owns a line
constexpr float EPS = 1e-6f;

// R7: XCD-local L2-side atomics. R5/R6 established: DEVICE-scope scattered
// atomics execute memory-side (~32B HBM writeback each, capped ~0.7 TB/s =
// 22-26 G/s) because per-XCD L2s aren't cross-coherent. Corollary under
// test: WORKGROUP-scope atomics into a replica private to this block's XCD
// (replica = HW_REG_XCC_ID) may execute in the local TCC (L2) at cache
// speed. All same-XCD blocks share that TCC -> RMWs still serialize
// atomically there; cross-dispatch visibility = standard end-of-kernel L2
// release (same mechanism g_part's plain stores already rely on).
// Split: x,y -> LDS u32 atomics (proven 2.7 cyc/lane => ~37us for 8.35M);
//        z,w -> workgroup-scope u64 atomics, line-spread per-XCC replicas.
//
// u64 format (g_part, g_rep slots): bits [63:44]=cnt, [43:0]=sse 2^-20.
//   per (station,XCD) slot: cnt ~1K < 2^20; sse ~1K*2.1*2^20 ~ 2^31 < 2^44.
// u32 LDS slot: bits [31:24]=cnt, [23:0]=sse 2^-12.
//   per (block,copy,station) slot Poisson(4): cnt << 256, sse << 2^24.
constexpr int CNT_SHIFT = 44;
constexpr unsigned long long SSE_MASK = (1ULL << 44) - 1;
constexpr double FP_INV_SCALE = 1.0 / 1048576.0;    // 2^-20
constexpr float FP_SCALE_20 = 1048576.0f;           // 2^20 (global path)

constexpr int U32_CNT_SHIFT = 24;
constexpr unsigned U32_SSE_MASK = (1u << 24) - 1;
constexpr float FP_SCALE_U32 = 4096.0f;             // 2^12 (LDS path)

#define MAX_PBLOCKS 512
#define RED_BLOCKS 32            // reduce kernel: 32 blocks x 32 stations each

__global__ __launch_bounds__(1024, 2) void nse_partial_kernel(
    const float4* __restrict__ yp4, const float4* __restrict__ yt4,
    const int4* __restrict__ st4, const float* __restrict__ yp,
    const float* __restrict__ yt, const int* __restrict__ st,
    unsigned long long* __restrict__ g_part,
    unsigned long long* __restrict__ g_rep, int n, int n4)
{
    __shared__ unsigned s_hist[NCOPY * NUM_S];
    for (int i = threadIdx.x; i < NCOPY * NUM_S; i += blockDim.x) {
        s_hist[i] = 0u;
    }
    __syncthreads();

    // Wave w uses LDS copy w&3.
    unsigned* hist = s_hist + ((threadIdx.x >> 6) & (NCOPY - 1)) * NUM_S;

    // This block's physical XCD -> its private global replica. A workgroup
    // never migrates off its CU, so xcc is constant for the block.
    unsigned xcc;
    asm volatile("s_getreg_b32 %0, hwreg(HW_REG_XCC_ID)" : "=s"(xcc));
    unsigned long long* grep =
        g_rep + (size_t)(xcc & (NXCD - 1)) * NUM_S * SLOT_U64;

    const int gtid = blockIdx.x * blockDim.x + threadIdx.x;
    const int stride = gridDim.x * blockDim.x;
    const unsigned ONE_CNT32 = 1u << U32_CNT_SHIFT;
    const unsigned long long ONE_CNT64 = 1ULL << CNT_SHIFT;

    for (int i = gtid; i < n4; i += stride) {
        float4 p = yp4[i];
        float4 t = yt4[i];
        int4 s = st4[i];
        float dx = p.x - t.x;
        float dy = p.y - t.y;
        float dz = p.z - t.z;
        float dw = p.w - t.w;
        // LDS pipe: x, y (u32 packed, 2^-12 fixed).
        unsigned fx = (unsigned)(dx * dx * FP_SCALE_U32 + 0.5f);
        unsigned fy = (unsigned)(dy * dy * FP_SCALE_U32 + 0.5f);
        atomicAdd(&hist[s.x], ONE_CNT32 | fx);
        atomicAdd(&hist[s.y], ONE_CNT32 | fy);
        // XCD-L2 pipe: z, w (u64 packed, 2^-20 fixed, workgroup scope so the
        // RMW can execute in this XCD's TCC instead of memory-side).
        unsigned fz = (unsigned)(dz * dz * FP_SCALE_20 + 0.5f);
        unsigned fw = (unsigned)(dw * dw * FP_SCALE_20 + 0.5f);
        __hip_atomic_fetch_add(&grep[(size_t)s.z * SLOT_U64],
                               ONE_CNT64 | (unsigned long long)fz,
                               __ATOMIC_RELAXED, __HIP_MEMORY_SCOPE_WORKGROUP);
        __hip_atomic_fetch_add(&grep[(size_t)s.w * SLOT_U64],
                               ONE_CNT64 | (unsigned long long)fw,
                               __ATOMIC_RELAXED, __HIP_MEMORY_SCOPE_WORKGROUP);
    }
    // Scalar tail (N divisible by 4 in practice): LDS path only.
    for (int i = n4 * 4 + gtid; i < n; i += stride) {
        float d = yp[i] - yt[i];
        unsigned f = (unsigned)(d * d * FP_SCALE_U32 + 0.5f);
        atomicAdd(&hist[st[i]], ONE_CNT32 | f);
    }
    __syncthreads();

    // Merge the 4 LDS copies, widen to u64 (sse<<8: 2^-12 -> 2^-20), store
    // coalesced to this block's private slot.
    unsigned long long* dst = g_part + (size_t)blockIdx.x * NUM_S;
    for (int i = threadIdx.x; i < NUM_S; i += blockDim.x) {
        unsigned long long h = 0ULL;
        #pragma unroll
        for (int c = 0; c < NCOPY; ++c) {
            unsigned v = s_hist[i + c * NUM_S];
            h += ((unsigned long long)(v >> U32_CNT_SHIFT) << CNT_SHIFT) |
                 ((unsigned long long)(v & U32_SSE_MASK) << 8);
        }
        dst[i] = h;
    }
}

// Kernel 2: 32 blocks; block j owns stations [32j, 32j+32). Sums the
// per-block partials AND the 8 per-XCD line-spread replicas; last arriving
// block (fenced ticket) writes the scalar.
__global__ __launch_bounds__(1024) void nse_reduce_kernel(
    const unsigned long long* __restrict__ g_part,
    const unsigned long long* __restrict__ g_rep,
    const float* __restrict__ station_std,
    unsigned int* __restrict__ g_ctl,
    float* __restrict__ out, int nblocks)
{
    __shared__ unsigned long long s_part[1024];
    const int t = threadIdx.x;
    const int s_lo = blockIdx.x * 32;
    const int ss = s_lo + (t & 31);
    const int chunk = t >> 5;                       // 0..31
    const int per_chunk = (nblocks + 31) >> 5;
    const int b0 = chunk * per_chunk;
    const int b1 = min(b0 + per_chunk, nblocks);

    unsigned long long acc = 0ULL;
    for (int b = b0; b < b1; ++b) {
        acc += g_part[(size_t)b * NUM_S + ss];      // coalesced across lanes
    }
    s_part[t] = acc;
    __syncthreads();

    float per = 0.0f, pres = 0.0f;
    if (t < 32) {
        unsigned long long h = 0ULL;
        #pragma unroll
        for (int c = 0; c < 32; ++c) {
            h += s_part[t + (c << 5)];
        }
        #pragma unroll
        for (int r = 0; r < NXCD; ++r) {
            h += g_rep[((size_t)r * NUM_S + s_lo + t) * SLOT_U64];
        }
        float cnt = (float)(unsigned)(h >> CNT_SHIFT);
        if (cnt > 0.0f) {
            float sse = (float)((double)(h & SSE_MASK) * FP_INV_SCALE);
            float sd = station_std[s_lo + t];
            float denom = (sd + EPS) * (sd + EPS);
            per = (sse / cnt) / denom;
            pres = 1.0f;
        }
    }

    // Wave-0 reduction over 64 lanes (lanes 32..63 carry zeros).
    if (t < 64) {
        #pragma unroll
        for (int o = 32; o > 0; o >>= 1) {
            per += __shfl_down(per, o, 64);
            pres += __shfl_down(pres, o, 64);
        }
        if (t == 0) {
            atomicAdd((float*)g_ctl + 1, per);
            atomicAdd((float*)g_ctl + 2, pres);
            __threadfence();                          // order adds before ticket
            unsigned int old = atomicAdd(g_ctl, 1u);
            if (old == gridDim.x - 1) {
                float sp = atomicAdd((float*)g_ctl + 1, 0.0f);  // coherent read
                float sc = atomicAdd((float*)g_ctl + 2, 0.0f);
                out[0] = sp / fmaxf(sc, 1.0f);
            }
        }
    }
}

extern "C" void kernel_launch(void* const* d_in, const int* in_sizes, int n_in,
                              void* d_out, int out_size, void* d_ws, size_t ws_size,
                              hipStream_t stream) {
    const float* y_pred = (const float*)d_in[0];
    const float* y_true = (const float*)d_in[1];
    const int* stations = (const int*)d_in[2];
    const float* station_std = (const float*)d_in[3];
    float* out = (float*)d_out;

    const int n = in_sizes[0];
    const int n4 = n / 4;

    const size_t rep_bytes = (size_t)NXCD * NUM_S * SLOT_U64 * 8;  // 512KB

    // Workspace: [0,64) ctl | [64, 64+512K) g_rep | then g_part.
    unsigned int* g_ctl = (unsigned int*)d_ws;
    unsigned long long* g_rep =
        (unsigned long long*)((char*)d_ws + 64);
    unsigned long long* g_part =
        (unsigned long long*)((char*)d_ws + 64 + rep_bytes);

    // ctl + replicas must be zero before the partial kernel's atomics land.
    hipMemsetAsync(d_ws, 0, 64 + rep_bytes, stream);

    long long avail =
        ((long long)ws_size - 64 - (long long)rep_bytes) / (NUM_S * 8);
    int npart = (int)(avail < 1 ? 1 : (avail > MAX_PBLOCKS ? MAX_PBLOCKS : avail));

    dim3 grid1(npart);
    dim3 block(1024);
    nse_partial_kernel<<<grid1, block, 0, stream>>>(
        (const float4*)y_pred, (const float4*)y_true, (const int4*)stations,
        y_pred, y_true, stations, g_part, g_rep, n, n4);

    dim3 grid2(RED_BLOCKS);
    nse_reduce_kernel<<<grid2, block, 0, stream>>>(
        g_part, g_rep, station_std, g_ctl, out, npart);
}

// Round 8
// 215.396 us; speedup vs baseline: 2.3333x; 2.3333x over previous
//
#include <hip/hip_runtime.h>

#define NUM_S 1024
#define NWAVE 16           // waves per 1024-thread block; one private copy each
constexpr float EPS = 1e-6f;

// R8: atomic-free LDS histogram. R2/R4/R7 established the rooflines:
//  - LDS atomic unit: ~173 cyc per scattered wave ds_add (per-OP cost;
//    width-independent, contention-independent) -> 73.5us for 16.7M.
//  - global atomics: memory-side, ~32B HBM writeback, ~0.7 TB/s, scope
//    hint ignored. Closed.
// This round: per-WAVE private u32 histograms + NON-atomic read-add-write
// (plain ds ops run ~15-30x faster per op than the atomic unit), with
// intra-wave same-station duplicates resolved in registers via 10-ballot
// peer matching + leader serialization (expected ~1.9 rounds/64 lanes).
// Trades the saturated atomic unit for the idle VALU + plain LDS path.
//
// u32 LDS slot: bits [31:24]=cnt, [23:0]=sse in 2^-12 fixed point.
//   Per (wave,station) slot: 4096 elements/wave over 1024 stations =
//   Poisson(4) -> cnt << 256; sse < ~20*61*4096 ~= 5M < 2^24.
// u64 g_part slot: bits [63:44]=cnt, [43:0]=sse in 2^-20 (sse<<8 widen).
constexpr int CNT_SHIFT = 44;
constexpr unsigned long long SSE_MASK = (1ULL << 44) - 1;
constexpr double FP_INV_SCALE = 1.0 / 1048576.0;    // 2^-20

constexpr int U32_CNT_SHIFT = 24;
constexpr unsigned U32_SSE_MASK = (1u << 24) - 1;
constexpr float FP_SCALE_U32 = 4096.0f;             // 2^12
constexpr unsigned ONE_CNT32 = 1u << U32_CNT_SHIFT;

#define MAX_PBLOCKS 512
#define RED_BLOCKS 32            // reduce kernel: 32 blocks x 32 stations each

// Add val into this wave's private histogram at station s, non-atomically.
// Correctness: per-wave copy kills inter-wave races; intra-wave duplicates
// are grouped via ballot-matching and serialized (one leader RMW per group
// per round). volatile forces a real ds_read/ds_write each round so the
// compiler cannot hoist the read past other lanes' writes.
__device__ __forceinline__ void accum_one(unsigned* hist, int s, unsigned val)
{
    const int lane = threadIdx.x & 63;
    // Peer mask: active lanes with identical station (10 bits).
    unsigned long long peers = ~0ULL;
    #pragma unroll
    for (int b = 0; b < 10; ++b) {
        unsigned long long vote = __ballot((s >> b) & 1);
        peers &= ((s >> b) & 1) ? vote : ~vote;
    }
    bool done = false;
    for (;;) {
        unsigned long long rem = __ballot(!done);   // active, not yet written
        if (rem == 0ULL) break;
        if (!done) {
            // Lowest remaining lane of my group writes this round. rem
            // also masks out inactive lanes that polluted ~vote bits.
            int leader = __ffsll(peers & rem) - 1;
            if (leader == lane) {
                volatile unsigned* h = hist + s;
                *h = *h + val;                      // plain ds_read+add+write
                done = true;
            }
        }
    }
}

__global__ __launch_bounds__(1024, 2) void nse_partial_kernel(
    const float4* __restrict__ yp4, const float4* __restrict__ yt4,
    const int4* __restrict__ st4, const float* __restrict__ yp,
    const float* __restrict__ yt, const int* __restrict__ st,
    unsigned long long* __restrict__ g_part,
    unsigned int* __restrict__ g_ctl, int n, int n4)
{
    __shared__ unsigned s_hist[NWAVE * NUM_S];      // 64 KB: per-wave copies
    for (int i = threadIdx.x; i < NWAVE * NUM_S; i += blockDim.x) {
        s_hist[i] = 0u;
    }
    if (blockIdx.x == 0 && threadIdx.x == 0) {
        g_ctl[0] = 0u;                 // arrival counter for reduce kernel
        ((float*)g_ctl)[1] = 0.0f;     // sum of per-station terms
        ((float*)g_ctl)[2] = 0.0f;     // n_present
    }
    __syncthreads();

    unsigned* hist = s_hist + (threadIdx.x >> 6) * NUM_S;  // my wave's copy

    const int gtid = blockIdx.x * blockDim.x + threadIdx.x;
    const int stride = gridDim.x * blockDim.x;

    for (int i = gtid; i < n4; i += stride) {
        float4 p = yp4[i];
        float4 t = yt4[i];
        int4 s = st4[i];
        float dx = p.x - t.x;
        float dy = p.y - t.y;
        float dz = p.z - t.z;
        float dw = p.w - t.w;
        unsigned fx = (unsigned)(dx * dx * FP_SCALE_U32 + 0.5f);
        unsigned fy = (unsigned)(dy * dy * FP_SCALE_U32 + 0.5f);
        unsigned fz = (unsigned)(dz * dz * FP_SCALE_U32 + 0.5f);
        unsigned fw = (unsigned)(dw * dw * FP_SCALE_U32 + 0.5f);
        accum_one(hist, s.x, ONE_CNT32 | fx);
        accum_one(hist, s.y, ONE_CNT32 | fy);
        accum_one(hist, s.z, ONE_CNT32 | fz);
        accum_one(hist, s.w, ONE_CNT32 | fw);
    }
    // Scalar tail (empty for n%4==0): atomic into MY wave's copy is safe —
    // no other wave touches this copy, and it orders after my plain ops.
    for (int i = n4 * 4 + gtid; i < n; i += stride) {
        float d = yp[i] - yt[i];
        unsigned f = (unsigned)(d * d * FP_SCALE_U32 + 0.5f);
        atomicAdd(&hist[st[i]], ONE_CNT32 | f);
    }
    __syncthreads();

    // Merge the 16 wave copies, widen to u64 (sse<<8: 2^-12 -> 2^-20),
    // store coalesced to this block's private slot.
    unsigned long long* dst = g_part + (size_t)blockIdx.x * NUM_S;
    for (int i = threadIdx.x; i < NUM_S; i += blockDim.x) {
        unsigned long long h = 0ULL;
        #pragma unroll
        for (int c = 0; c < NWAVE; ++c) {
            unsigned v = s_hist[i + c * NUM_S];
            h += ((unsigned long long)(v >> U32_CNT_SHIFT) << CNT_SHIFT) |
                 ((unsigned long long)(v & U32_SSE_MASK) << 8);
        }
        dst[i] = h;
    }
}

// Kernel 2 (unchanged R4 structure): 32 blocks; block j owns stations
// [32j, 32j+32); last arriving block (fenced ticket) writes the scalar.
__global__ __launch_bounds__(1024) void nse_reduce_kernel(
    const unsigned long long* __restrict__ g_part,
    const float* __restrict__ station_std,
    unsigned int* __restrict__ g_ctl,
    float* __restrict__ out, int nblocks)
{
    __shared__ unsigned long long s_part[1024];
    const int t = threadIdx.x;
    const int s_lo = blockIdx.x * 32;
    const int ss = s_lo + (t & 31);
    const int chunk = t >> 5;                       // 0..31
    const int per_chunk = (nblocks + 31) >> 5;
    const int b0 = chunk * per_chunk;
    const int b1 = min(b0 + per_chunk, nblocks);

    unsigned long long acc = 0ULL;
    for (int b = b0; b < b1; ++b) {
        acc += g_part[(size_t)b * NUM_S + ss];      // coalesced across lanes
    }
    s_part[t] = acc;
    __syncthreads();

    float per = 0.0f, pres = 0.0f;
    if (t < 32) {
        unsigned long long h = 0ULL;
        #pragma unroll
        for (int c = 0; c < 32; ++c) {
            h += s_part[t + (c << 5)];
        }
        float cnt = (float)(unsigned)(h >> CNT_SHIFT);
        if (cnt > 0.0f) {
            float sse = (float)((double)(h & SSE_MASK) * FP_INV_SCALE);
            float sd = station_std[s_lo + t];
            float denom = (sd + EPS) * (sd + EPS);
            per = (sse / cnt) / denom;
            pres = 1.0f;
        }
    }

    // Wave-0 reduction over 64 lanes (lanes 32..63 carry zeros).
    if (t < 64) {
        #pragma unroll
        for (int o = 32; o > 0; o >>= 1) {
            per += __shfl_down(per, o, 64);
            pres += __shfl_down(pres, o, 64);
        }
        if (t == 0) {
            atomicAdd((float*)g_ctl + 1, per);
            atomicAdd((float*)g_ctl + 2, pres);
            __threadfence();                          // order adds before ticket
            unsigned int old = atomicAdd(g_ctl, 1u);
            if (old == gridDim.x - 1) {
                float sp = atomicAdd((float*)g_ctl + 1, 0.0f);  // coherent read
                float sc = atomicAdd((float*)g_ctl + 2, 0.0f);
                out[0] = sp / fmaxf(sc, 1.0f);
            }
        }
    }
}

extern "C" void kernel_launch(void* const* d_in, const int* in_sizes, int n_in,
                              void* d_out, int out_size, void* d_ws, size_t ws_size,
                              hipStream_t stream) {
    const float* y_pred = (const float*)d_in[0];
    const float* y_true = (const float*)d_in[1];
    const int* stations = (const int*)d_in[2];
    const float* station_std = (const float*)d_in[3];
    float* out = (float*)d_out;

    const int n = in_sizes[0];
    const int n4 = n / 4;

    // Workspace layout: [0,64) control block; [64, ...) g_part partials.
    unsigned int* g_ctl = (unsigned int*)d_ws;
    unsigned long long* g_part =
        (unsigned long long*)((char*)d_ws + 64);

    // Size the partial grid to the workspace (expected: full 512 blocks).
    long long avail = ((long long)ws_size - 64) / (NUM_S * 8);
    int npart = (int)(avail < 1 ? 1 : (avail > MAX_PBLOCKS ? MAX_PBLOCKS : avail));

    dim3 grid1(npart);
    dim3 block(1024);
    nse_partial_kernel<<<grid1, block, 0, stream>>>(
        (const float4*)y_pred, (const float4*)y_true, (const int4*)stations,
        y_pred, y_true, stations, g_part, g_ctl, n, n4);

    dim3 grid2(RED_BLOCKS);
    nse_reduce_kernel<<<grid2, block, 0, stream>>>(
        g_part, station_std, g_ctl, out, npart);
}

// Round 10
// 205.685 us; speedup vs baseline: 2.4435x; 1.0472x over previous
//
#include <hip/hip_runtime.h>

#define NUM_S 1024
#define NWAVE 16           // waves per 1024-thread block; one private copy each
constexpr float EPS = 1e-6f;

// R9 (resubmit; prior attempt was an infra acquisition timeout):
// tag-verified non-atomic LDS histogram.
// Ladder so far: LDS atomics = 173cyc/wave-op (per-op; width/contention
// independent) -> 74us. Global atomics = memory-side 0.7TB/s, scope hint
// ignored -> closed. R8 ballot-dedup = correct but VALU-bound (61%) -> 86us.
// This round: per-wave copies + write-READBACK verification (wave lockstep:
// simultaneous ds_write lands one winner; losers see foreign tag and retry
// with the winner's value). ~8 VALU + ~3.3 LDS wave-ops per element.
//
// u32 LDS slot: tag[31:26]=last-writer lane, cnt[25:21], sse[20:0] @2^-8.
//   Per (wave,station) slot sees Poisson(2) elements: P(cnt>=32)~1e-19;
//   sse <= 31 * d2max(~85) * 256 = 675K < 2^21. Carry into tag impossible.
// u64 g_part slot: bits [63:44]=cnt, [43:0]=sse @2^-20 (sse<<12 widen).
constexpr int CNT_SHIFT = 44;
constexpr unsigned long long SSE_MASK = (1ULL << 44) - 1;
constexpr double FP_INV_SCALE = 1.0 / 1048576.0;    // 2^-20

constexpr unsigned DATA_MASK = 0x03FFFFFFu;         // [25:0]
constexpr unsigned SSE21_MASK = 0x001FFFFFu;        // [20:0]
constexpr int CNT21_SHIFT = 21;
constexpr float FP_SCALE_U32 = 256.0f;              // 2^8
constexpr unsigned ONE_CNT21 = 1u << CNT21_SHIFT;

#define MAX_PBLOCKS 512
#define RED_BLOCKS 32            // reduce kernel: 32 blocks x 32 stations each

// Non-atomic accumulate into this wave's private histogram.
// Wave lockstep: all active lanes' ds_write to the same address collapse to
// ONE winner per HW; the readback (same-wave, same-address, later in issue
// order) shows whose tag landed. Losers retry from the winner's value --
// terminates in max-multiplicity rounds (expected ~2 for 64 keys/1024 bins).
// volatile => every access is a real ds op in strict program order, so the
// sequential x,y,z,w calls cannot interleave (same-lane dup stations safe).
__device__ __forceinline__ void accum_tag(volatile unsigned* hist, int s,
                                          unsigned val, unsigned mytag)
{
    unsigned h = hist[s];
    for (;;) {
        unsigned nv = ((h & DATA_MASK) + val) | mytag;
        hist[s] = nv;
        unsigned rb = hist[s];
        if (rb == nv) break;     // my tag+data landed: add is in
        h = rb;                  // lost to another lane: fold and retry
    }
}

__global__ __launch_bounds__(1024, 2) void nse_partial_kernel(
    const float4* __restrict__ yp4, const float4* __restrict__ yt4,
    const int4* __restrict__ st4, const float* __restrict__ yp,
    const float* __restrict__ yt, const int* __restrict__ st,
    unsigned long long* __restrict__ g_part,
    unsigned int* __restrict__ g_ctl, int n, int n4)
{
    __shared__ unsigned s_hist[NWAVE * NUM_S];      // 64 KB: per-wave copies
    for (int i = threadIdx.x; i < NWAVE * NUM_S; i += blockDim.x) {
        s_hist[i] = 0u;
    }
    if (blockIdx.x == 0 && threadIdx.x == 0) {
        g_ctl[0] = 0u;                 // arrival counter for reduce kernel
        ((float*)g_ctl)[1] = 0.0f;     // sum of per-station terms
        ((float*)g_ctl)[2] = 0.0f;     // n_present
    }
    __syncthreads();

    volatile unsigned* hist = s_hist + (threadIdx.x >> 6) * NUM_S;
    const unsigned mytag = (threadIdx.x & 63u) << 26;

    const int gtid = blockIdx.x * blockDim.x + threadIdx.x;
    const int stride = gridDim.x * blockDim.x;

    for (int i = gtid; i < n4; i += stride) {
        float4 p = yp4[i];
        float4 t = yt4[i];
        int4 s = st4[i];
        float dx = p.x - t.x;
        float dy = p.y - t.y;
        float dz = p.z - t.z;
        float dw = p.w - t.w;
        unsigned fx = (unsigned)(dx * dx * FP_SCALE_U32 + 0.5f);
        unsigned fy = (unsigned)(dy * dy * FP_SCALE_U32 + 0.5f);
        unsigned fz = (unsigned)(dz * dz * FP_SCALE_U32 + 0.5f);
        unsigned fw = (unsigned)(dw * dw * FP_SCALE_U32 + 0.5f);
        accum_tag(hist, s.x, ONE_CNT21 | fx, mytag);
        accum_tag(hist, s.y, ONE_CNT21 | fy, mytag);
        accum_tag(hist, s.z, ONE_CNT21 | fz, mytag);
        accum_tag(hist, s.w, ONE_CNT21 | fw, mytag);
    }
    // Scalar tail (empty for n%4==0): same path.
    for (int i = n4 * 4 + gtid; i < n; i += stride) {
        float d = yp[i] - yt[i];
        unsigned f = (unsigned)(d * d * FP_SCALE_U32 + 0.5f);
        accum_tag(hist, st[i], ONE_CNT21 | f, mytag);
    }
    __syncthreads();

    // Merge the 16 wave copies (strip tags), widen to u64
    // (sse: 2^-8 -> 2^-20 is <<12), store coalesced to this block's slot.
    unsigned long long* dst = g_part + (size_t)blockIdx.x * NUM_S;
    for (int i = threadIdx.x; i < NUM_S; i += blockDim.x) {
        unsigned long long h = 0ULL;
        #pragma unroll
        for (int c = 0; c < NWAVE; ++c) {
            unsigned v = s_hist[i + c * NUM_S] & DATA_MASK;
            h += ((unsigned long long)(v >> CNT21_SHIFT) << CNT_SHIFT) |
                 ((unsigned long long)(v & SSE21_MASK) << 12);
        }
        dst[i] = h;
    }
}

// Kernel 2 (unchanged): 32 blocks; block j owns stations [32j, 32j+32);
// last arriving block (fenced ticket) writes the scalar.
__global__ __launch_bounds__(1024) void nse_reduce_kernel(
    const unsigned long long* __restrict__ g_part,
    const float* __restrict__ station_std,
    unsigned int* __restrict__ g_ctl,
    float* __restrict__ out, int nblocks)
{
    __shared__ unsigned long long s_part[1024];
    const int t = threadIdx.x;
    const int s_lo = blockIdx.x * 32;
    const int ss = s_lo + (t & 31);
    const int chunk = t >> 5;                       // 0..31
    const int per_chunk = (nblocks + 31) >> 5;
    const int b0 = chunk * per_chunk;
    const int b1 = min(b0 + per_chunk, nblocks);

    unsigned long long acc = 0ULL;
    for (int b = b0; b < b1; ++b) {
        acc += g_part[(size_t)b * NUM_S + ss];      // coalesced across lanes
    }
    s_part[t] = acc;
    __syncthreads();

    float per = 0.0f, pres = 0.0f;
    if (t < 32) {
        unsigned long long h = 0ULL;
        #pragma unroll
        for (int c = 0; c < 32; ++c) {
            h += s_part[t + (c << 5)];
        }
        float cnt = (float)(unsigned)(h >> CNT_SHIFT);
        if (cnt > 0.0f) {
            float sse = (float)((double)(h & SSE_MASK) * FP_INV_SCALE);
            float sd = station_std[s_lo + t];
            float denom = (sd + EPS) * (sd + EPS);
            per = (sse / cnt) / denom;
            pres = 1.0f;
        }
    }

    // Wave-0 reduction over 64 lanes (lanes 32..63 carry zeros).
    if (t < 64) {
        #pragma unroll
        for (int o = 32; o > 0; o >>= 1) {
            per += __shfl_down(per, o, 64);
            pres += __shfl_down(pres, o, 64);
        }
        if (t == 0) {
            atomicAdd((float*)g_ctl + 1, per);
            atomicAdd((float*)g_ctl + 2, pres);
            __threadfence();                          // order adds before ticket
            unsigned int old = atomicAdd(g_ctl, 1u);
            if (old == gridDim.x - 1) {
                float sp = atomicAdd((float*)g_ctl + 1, 0.0f);  // coherent read
                float sc = atomicAdd((float*)g_ctl + 2, 0.0f);
                out[0] = sp / fmaxf(sc, 1.0f);
            }
        }
    }
}

extern "C" void kernel_launch(void* const* d_in, const int* in_sizes, int n_in,
                              void* d_out, int out_size, void* d_ws, size_t ws_size,
                              hipStream_t stream) {
    const float* y_pred = (const float*)d_in[0];
    const float* y_true = (const float*)d_in[1];
    const int* stations = (const int*)d_in[2];
    const float* station_std = (const float*)d_in[3];
    float* out = (float*)d_out;

    const int n = in_sizes[0];
    const int n4 = n / 4;

    // Workspace layout: [0,64) control block; [64, ...) g_part partials.
    unsigned int* g_ctl = (unsigned int*)d_ws;
    unsigned long long* g_part =
        (unsigned long long*)((char*)d_ws + 64);

    // Size the partial grid to the workspace (expected: full 512 blocks).
    long long avail = ((long long)ws_size - 64) / (NUM_S * 8);
    int npart = (int)(avail < 1 ? 1 : (avail > MAX_PBLOCKS ? MAX_PBLOCKS : avail));

    dim3 grid1(npart);
    dim3 block(1024);
    nse_partial_kernel<<<grid1, block, 0, stream>>>(
        (const float4*)y_pred, (const float4*)y_true, (const int4*)stations,
        y_pred, y_true, stations, g_part, g_ctl, n, n4);

    dim3 grid2(RED_BLOCKS);
    nse_reduce_kernel<<<grid2, block, 0, stream>>>(
        g_part, station_std, g_ctl, out, npart);
}